// Round 2
// baseline (1298.576 us; speedup 1.0000x reference)
//
#include <hip/hip_runtime.h>
#include <hip/hip_bf16.h>

#define N_NODES 100000
#define N_EDGES 1600000
#define NFEAT   200
#define NHID    128
#define NOUT    64
#define BN_EPS  1e-5f

static constexpr int SCAN_NB = (N_NODES + 255) / 256;   // 391 blocks in level-1 scan

// ---------------------------------------------------------------- init
__global__ __launch_bounds__(256) void init_kernel(int* counts, float* deg, float* stats)
{
    int i = blockIdx.x * 256 + threadIdx.x;
    if (i <= N_NODES) counts[i] = 0;
    if (i <  N_NODES) deg[i]    = 1.0f;          // self-loop weight
    if (i <  512)     stats[i]  = 0.0f;          // stats0 (256) + stats1 (256)
}

// ------------------------------------------------------------ histogram
__global__ __launch_bounds__(256) void hist_kernel(const int* __restrict__ adj,
                                                   const float* __restrict__ wt,
                                                   int* __restrict__ counts,
                                                   float* __restrict__ deg)
{
    int e = blockIdx.x * 256 + threadIdx.x;
    if (e >= N_EDGES) return;
    int d = adj[N_EDGES + e];                     // dst row
    atomicAdd(&counts[d], 1);
    atomicAdd(&deg[d], wt[e]);
}

// ---------------------------------------------------------------- dinv
__global__ __launch_bounds__(256) void dinv_kernel(float* deg)
{
    int i = blockIdx.x * 256 + threadIdx.x;
    if (i >= N_NODES) return;
    float d = deg[i];
    deg[i] = (d > 0.f) ? rsqrtf(d) : 0.f;         // in-place -> dinv
}

// ------------------------------------------------------- scan level 1
__global__ __launch_bounds__(256) void scan_block(const int* __restrict__ counts,
                                                  int* __restrict__ rowptr,
                                                  int* __restrict__ bsums)
{
    __shared__ int s[256];
    int t = threadIdx.x;
    int i = blockIdx.x * 256 + t;
    int v = (i < N_NODES) ? counts[i] : 0;
    s[t] = v; __syncthreads();
    #pragma unroll
    for (int off = 1; off < 256; off <<= 1) {
        int x = (t >= off) ? s[t - off] : 0;
        __syncthreads();
        s[t] += x;
        __syncthreads();
    }
    if (i < N_NODES) rowptr[i] = s[t] - v;        // block-local exclusive
    if (t == 255) bsums[blockIdx.x] = s[255];
}

// ------------------------------------------------------- scan level 2
__global__ __launch_bounds__(512) void scan_top(int* bsums)
{
    __shared__ int s[512];
    int t = threadIdx.x;
    int v = (t < SCAN_NB) ? bsums[t] : 0;
    s[t] = v; __syncthreads();
    #pragma unroll
    for (int off = 1; off < 512; off <<= 1) {
        int x = (t >= off) ? s[t - off] : 0;
        __syncthreads();
        s[t] += x;
        __syncthreads();
    }
    if (t < SCAN_NB) bsums[t] = s[t] - v;         // exclusive
}

// ------------------------------------------------- scan add + cursor
__global__ __launch_bounds__(256) void scan_add(int* __restrict__ rowptr,
                                                const int* __restrict__ bsums,
                                                int* __restrict__ cursor)
{
    int i = blockIdx.x * 256 + threadIdx.x;
    if (i < N_NODES) {
        int r = rowptr[i] + bsums[i >> 8];
        rowptr[i] = r;
        cursor[i] = r;
    }
    if (i == 0) rowptr[N_NODES] = N_EDGES;
}

// ------------------------------------------------------------ CSR fill
__global__ __launch_bounds__(256) void fill_kernel(const int* __restrict__ adj,
                                                   const float* __restrict__ wt,
                                                   const float* __restrict__ dinv,
                                                   int* __restrict__ cursor,
                                                   int* __restrict__ col_src,
                                                   float* __restrict__ col_norm)
{
    int e = blockIdx.x * 256 + threadIdx.x;
    if (e >= N_EDGES) return;
    int s = adj[e];
    int d = adj[N_EDGES + e];
    int pos = atomicAdd(&cursor[d], 1);
    col_src[pos]  = s;
    col_norm[pos] = dinv[s] * wt[e] * dinv[d];
}

// ---------------------------------------------------------------- GEMM
// C[M,NC] = A[M,K] @ W[K,NC]  (+C if ACCUM) (bias+relu if BIASRELU)
template<int NC, bool ACCUM, bool BIASRELU>
__global__ __launch_bounds__(256) void gemm_kernel(const float* __restrict__ A,
                                                   const float* __restrict__ W,
                                                   const float* __restrict__ bias,
                                                   float* __restrict__ C,
                                                   int M, int K)
{
    constexpr int BM = 64, BK = 64;
    constexpr int COLG = NC / 8;          // 16 or 8 col-groups
    constexpr int RPT  = NC / 32;         // rows per thread: 4 or 2
    __shared__ float a_t[BM][BK + 1];
    __shared__ float w_t[BK][NC];

    int t  = threadIdx.x;
    int m0 = blockIdx.x * BM;
    int c0 = (t % COLG) * 8;
    int r0 = (t / COLG) * RPT;

    float acc[RPT][8];
    #pragma unroll
    for (int j = 0; j < RPT; ++j)
        #pragma unroll
        for (int i = 0; i < 8; ++i) acc[j][i] = 0.f;

    for (int k0 = 0; k0 < K; k0 += BK) {
        // stage W[k0:k0+64, :] -> LDS
        constexpr int WF4 = BK * NC / 4 / 256;
        #pragma unroll
        for (int i = 0; i < WF4; ++i) {
            int idx = t + i * 256;                 // float4 index
            int kr  = idx / (NC / 4);
            int c4  = (idx % (NC / 4)) * 4;
            float4 v = make_float4(0.f, 0.f, 0.f, 0.f);
            if (k0 + kr < K) v = *(const float4*)&W[(size_t)(k0 + kr) * NC + c4];
            *(float4*)&w_t[kr][c4] = v;
        }
        // stage A[m0:m0+64, k0:k0+64] -> LDS
        #pragma unroll
        for (int i = 0; i < 4; ++i) {
            int idx = t + i * 256;
            int ar  = idx / 16;
            int ac  = (idx % 16) * 4;
            float4 v = make_float4(0.f, 0.f, 0.f, 0.f);
            int m = m0 + ar, k = k0 + ac;
            if (m < M && k < K) v = *(const float4*)&A[(size_t)m * K + k];
            a_t[ar][ac]     = v.x;
            a_t[ar][ac + 1] = v.y;
            a_t[ar][ac + 2] = v.z;
            a_t[ar][ac + 3] = v.w;
        }
        __syncthreads();

        #pragma unroll 8
        for (int kk = 0; kk < BK; ++kk) {
            float4 w0 = *(float4*)&w_t[kk][c0];
            float4 w1 = *(float4*)&w_t[kk][c0 + 4];
            #pragma unroll
            for (int j = 0; j < RPT; ++j) {
                float a = a_t[r0 + j][kk];
                acc[j][0] += a * w0.x; acc[j][1] += a * w0.y;
                acc[j][2] += a * w0.z; acc[j][3] += a * w0.w;
                acc[j][4] += a * w1.x; acc[j][5] += a * w1.y;
                acc[j][6] += a * w1.z; acc[j][7] += a * w1.w;
            }
        }
        __syncthreads();
    }

    float bi[8];
    if (BIASRELU) {
        #pragma unroll
        for (int i = 0; i < 8; ++i) bi[i] = bias[c0 + i];
    }
    #pragma unroll
    for (int j = 0; j < RPT; ++j) {
        int m = m0 + r0 + j;
        if (m >= M) continue;
        float o[8];
        #pragma unroll
        for (int i = 0; i < 8; ++i) o[i] = acc[j][i];
        if (ACCUM) {
            float4 p0 = *(float4*)&C[(size_t)m * NC + c0];
            float4 p1 = *(float4*)&C[(size_t)m * NC + c0 + 4];
            o[0] += p0.x; o[1] += p0.y; o[2] += p0.z; o[3] += p0.w;
            o[4] += p1.x; o[5] += p1.y; o[6] += p1.z; o[7] += p1.w;
        }
        if (BIASRELU) {
            #pragma unroll
            for (int i = 0; i < 8; ++i) o[i] = fmaxf(o[i] + bi[i], 0.f);
        }
        *(float4*)&C[(size_t)m * NC + c0]     = make_float4(o[0], o[1], o[2], o[3]);
        *(float4*)&C[(size_t)m * NC + c0 + 4] = make_float4(o[4], o[5], o[6], o[7]);
    }
}

// --------------------------------------------------------- aggregation
// out[n,f] = relu( dinv[n]^2 * h[n,f] + sum_e norm[e]*h[src[e],f] + bias[f] )
__global__ __launch_bounds__(256) void agg_kernel(const float* __restrict__ h,
                                                  const float* __restrict__ bias,
                                                  const float* __restrict__ dinv,
                                                  const int* __restrict__ rowptr,
                                                  const int* __restrict__ col_src,
                                                  const float* __restrict__ col_norm,
                                                  float* __restrict__ out)
{
    int node = blockIdx.x * 4 + (threadIdx.x >> 6);
    if (node >= N_NODES) return;
    int lane = threadIdx.x & 63;
    int f0 = lane * 2;

    float di = dinv[node];
    float2 hv = *(const float2*)&h[(size_t)node * NHID + f0];
    float ax = di * di * hv.x;
    float ay = di * di * hv.y;

    int beg = rowptr[node], end = rowptr[node + 1];
    for (int e = beg; e < end; ++e) {
        int s = col_src[e];
        float nw = col_norm[e];
        float2 v = *(const float2*)&h[(size_t)s * NHID + f0];
        ax += nw * v.x;
        ay += nw * v.y;
    }
    float2 b = *(const float2*)&bias[f0];
    float2 o;
    o.x = fmaxf(ax + b.x, 0.f);
    o.y = fmaxf(ay + b.y, 0.f);
    *(float2*)&out[(size_t)node * NHID + f0] = o;
}

// --------------------------------------------------------------- stats
__global__ __launch_bounds__(256) void stats_kernel(const float* __restrict__ h,
                                                    float* __restrict__ st)
{
    __shared__ float ls[256], ls2[256];
    int t = threadIdx.x;
    int c = t & 127, half = t >> 7;
    float s = 0.f, s2 = 0.f;
    for (int r = blockIdx.x * 2 + half; r < N_NODES; r += gridDim.x * 2) {
        float v = h[(size_t)r * NHID + c];
        s += v; s2 += v * v;
    }
    ls[t] = s; ls2[t] = s2; __syncthreads();
    if (half == 0) {
        s  += ls[t + 128];
        s2 += ls2[t + 128];
        atomicAdd(&st[c], s);
        atomicAdd(&st[128 + c], s2);
    }
}

// --------------------------------------------------------- bn finalize
__global__ __launch_bounds__(128) void bn_finalize(const float* __restrict__ st,
                                                   const float* __restrict__ g,
                                                   const float* __restrict__ beta,
                                                   float* __restrict__ scsh)
{
    int c = threadIdx.x;
    float mean = st[c] / (float)N_NODES;
    float var  = st[128 + c] / (float)N_NODES - mean * mean;
    float inv  = rsqrtf(var + BN_EPS);
    float sc   = g[c] * inv;
    scsh[c]       = sc;
    scsh[128 + c] = beta[c] - mean * sc;
}

// ------------------------------------------------------------ bn apply
__global__ __launch_bounds__(256) void bn_apply(float* __restrict__ h,
                                                const float* __restrict__ scsh)
{
    size_t idx = (size_t)blockIdx.x * 256 + threadIdx.x;   // float4 id
    if (idx >= (size_t)N_NODES * (NHID / 4)) return;
    int c = (idx & (NHID / 4 - 1)) * 4;
    float4 sc = *(const float4*)&scsh[c];
    float4 sh = *(const float4*)&scsh[128 + c];
    float4 v  = *(float4*)&h[idx * 4];
    v.x = sc.x * v.x + sh.x;
    v.y = sc.y * v.y + sh.y;
    v.z = sc.z * v.z + sh.z;
    v.w = sc.w * v.w + sh.w;
    *(float4*)&h[idx * 4] = v;
}

// ---------------------------------------------------------------- host
extern "C" void kernel_launch(void* const* d_in, const int* in_sizes, int n_in,
                              void* d_out, int out_size, void* d_ws, size_t ws_size,
                              hipStream_t stream)
{
    const float* x     = (const float*)d_in[0];
    const int*   adj   = (const int*)d_in[1];
    const float* wt    = (const float*)d_in[2];
    const float* W1    = (const float*)d_in[3];
    const float* b1    = (const float*)d_in[4];
    const float* W2    = (const float*)d_in[5];
    const float* b2    = (const float*)d_in[6];
    const float* g1    = (const float*)d_in[7];
    const float* beta1 = (const float*)d_in[8];
    const float* g2    = (const float*)d_in[9];
    const float* beta2 = (const float*)d_in[10];
    const float* fc1W  = (const float*)d_in[11];
    const float* fc1b  = (const float*)d_in[12];
    const float* fc2W  = (const float*)d_in[13];
    const float* fc2b  = (const float*)d_in[14];
    float* out = (float*)d_out;

    // ---- workspace carve-up (256B aligned)
    char* p = (char*)d_ws;
    auto alloc = [&](size_t bytes) -> void* {
        void* r = (void*)p;
        p += (bytes + 255) & ~(size_t)255;
        return r;
    };
    float* dinv     = (float*)alloc((size_t)N_NODES * 4);        // deg -> dinv
    int*   counts   = (int*)  alloc((size_t)(N_NODES + 1) * 4);
    int*   rowptr   = (int*)  alloc((size_t)(N_NODES + 1) * 4);
    int*   cursor   = (int*)  alloc((size_t)N_NODES * 4);
    int*   col_src  = (int*)  alloc((size_t)N_EDGES * 4);
    float* col_norm = (float*)alloc((size_t)N_EDGES * 4);
    int*   bsums    = (int*)  alloc(1024 * 4);
    float* stats    = (float*)alloc(512 * 4);   // stats0 | stats1
    float* scsh     = (float*)alloc(256 * 4);
    float* t_buf    = (float*)alloc((size_t)N_NODES * NHID * 4);
    float* h1       = (float*)alloc((size_t)N_NODES * NHID * 4);
    float* h2       = (float*)alloc((size_t)N_NODES * NHID * 4);

    const int gN  = (N_NODES + 255) / 256;
    const int gN1 = (N_NODES + 256) / 256;
    const int gE  = (N_EDGES + 255) / 256;
    const int gM  = (N_NODES + 63) / 64;

    // ---- graph preprocessing (CSR by dst, shared by both convs)
    init_kernel<<<gN1, 256, 0, stream>>>(counts, dinv, stats);
    hist_kernel<<<gE, 256, 0, stream>>>(adj, wt, counts, dinv);
    dinv_kernel<<<gN, 256, 0, stream>>>(dinv);
    scan_block<<<SCAN_NB, 256, 0, stream>>>(counts, rowptr, bsums);
    scan_top<<<1, 512, 0, stream>>>(bsums);
    scan_add<<<SCAN_NB, 256, 0, stream>>>(rowptr, bsums, cursor);
    fill_kernel<<<gE, 256, 0, stream>>>(adj, wt, dinv, cursor, col_src, col_norm);

    // ---- conv1: t = x @ W1 ; h1 = BN(relu(agg(t)+b1))
    gemm_kernel<NHID, false, false><<<gM, 256, 0, stream>>>(x, W1, nullptr, t_buf, N_NODES, NFEAT);
    agg_kernel<<<(N_NODES + 3) / 4, 256, 0, stream>>>(t_buf, b1, dinv, rowptr, col_src, col_norm, h1);
    stats_kernel<<<1024, 256, 0, stream>>>(h1, stats);
    bn_finalize<<<1, 128, 0, stream>>>(stats, g1, beta1, scsh);
    bn_apply<<<(N_NODES * (NHID / 4) + 255) / 256, 256, 0, stream>>>(h1, scsh);

    // ---- conv2: t = h1 @ W2 ; h2 = BN(relu(agg(t)+b2))
    gemm_kernel<NHID, false, false><<<gM, 256, 0, stream>>>(h1, W2, nullptr, t_buf, N_NODES, NHID);
    agg_kernel<<<(N_NODES + 3) / 4, 256, 0, stream>>>(t_buf, b2, dinv, rowptr, col_src, col_norm, h2);
    stats_kernel<<<1024, 256, 0, stream>>>(h2, stats + 256);
    bn_finalize<<<1, 128, 0, stream>>>(stats + 256, g2, beta2, scsh);
    bn_apply<<<(N_NODES * (NHID / 4) + 255) / 256, 256, 0, stream>>>(h2, scsh);

    // ---- fc1: t = relu([x,h1,h2] @ fc1W + fc1b)   (3 accumulating GEMMs)
    gemm_kernel<NHID, false, false><<<gM, 256, 0, stream>>>(x,  fc1W,                    nullptr, t_buf, N_NODES, NFEAT);
    gemm_kernel<NHID, true,  false><<<gM, 256, 0, stream>>>(h1, fc1W + (size_t)NFEAT * NHID,          nullptr, t_buf, N_NODES, NHID);
    gemm_kernel<NHID, true,  true ><<<gM, 256, 0, stream>>>(h2, fc1W + (size_t)(NFEAT + NHID) * NHID, fc1b,    t_buf, N_NODES, NHID);

    // ---- fc2: out = relu(t @ fc2W + fc2b)
    gemm_kernel<NOUT, false, true><<<gM, 256, 0, stream>>>(t_buf, fc2W, fc2b, out, N_NODES, NHID);
}

// Round 7
// 1258.766 us; speedup vs baseline: 1.0316x; 1.0316x over previous
//
#include <hip/hip_runtime.h>
#include <hip/hip_bf16.h>

#define N_NODES 100000
#define N_EDGES 1600000
#define NFEAT   200
#define NHID    128
#define NOUT    64
#define BN_EPS  1e-5f

static constexpr int SCAN_NB = (N_NODES + 255) / 256;   // 391 blocks in level-1 scan

// ---------------------------------------------------------------- init
__global__ __launch_bounds__(256) void init_kernel(int* counts, float* deg, float* stats)
{
    int i = blockIdx.x * 256 + threadIdx.x;
    if (i <= N_NODES) counts[i] = 0;
    if (i <  N_NODES) deg[i]    = 1.0f;          // self-loop weight
    if (i <  512)     stats[i]  = 0.0f;          // stats0 (256) + stats1 (256)
}

// ------------------------------------------------------------ histogram
__global__ __launch_bounds__(256) void hist_kernel(const int* __restrict__ adj,
                                                   const float* __restrict__ wt,
                                                   int* __restrict__ counts,
                                                   float* __restrict__ deg)
{
    int e = blockIdx.x * 256 + threadIdx.x;
    if (e >= N_EDGES) return;
    int d = adj[N_EDGES + e];                     // dst row
    atomicAdd(&counts[d], 1);
    atomicAdd(&deg[d], wt[e]);
}

// ------------------------------------------------------- scan level 1
__global__ __launch_bounds__(256) void scan_block(const int* __restrict__ counts,
                                                  int* __restrict__ rowptr,
                                                  int* __restrict__ bsums)
{
    __shared__ int s[256];
    int t = threadIdx.x;
    int i = blockIdx.x * 256 + t;
    int v = (i < N_NODES) ? counts[i] : 0;
    s[t] = v; __syncthreads();
    #pragma unroll
    for (int off = 1; off < 256; off <<= 1) {
        int x = (t >= off) ? s[t - off] : 0;
        __syncthreads();
        s[t] += x;
        __syncthreads();
    }
    if (i < N_NODES) rowptr[i] = s[t] - v;        // block-local exclusive
    if (t == 255) bsums[blockIdx.x] = s[255];
}

// ------------------------------------------------------- scan level 2
__global__ __launch_bounds__(512) void scan_top(int* bsums)
{
    __shared__ int s[512];
    int t = threadIdx.x;
    int v = (t < SCAN_NB) ? bsums[t] : 0;
    s[t] = v; __syncthreads();
    #pragma unroll
    for (int off = 1; off < 512; off <<= 1) {
        int x = (t >= off) ? s[t - off] : 0;
        __syncthreads();
        s[t] += x;
        __syncthreads();
    }
    if (t < SCAN_NB) bsums[t] = s[t] - v;         // exclusive
}

// --------------------------------------- scan add + cursor + dinv fuse
__global__ __launch_bounds__(256) void scan_add(int* __restrict__ rowptr,
                                                const int* __restrict__ bsums,
                                                int* __restrict__ cursor,
                                                float* __restrict__ deg)
{
    int i = blockIdx.x * 256 + threadIdx.x;
    if (i < N_NODES) {
        int r = rowptr[i] + bsums[i >> 8];
        rowptr[i] = r;
        cursor[i] = r;
        float d = deg[i];
        deg[i] = (d > 0.f) ? rsqrtf(d) : 0.f;     // deg -> dinv in place
    }
    if (i == 0) rowptr[N_NODES] = N_EDGES;
}

// ------------------------------------------------------------ CSR fill
__global__ __launch_bounds__(256) void fill_kernel(const int* __restrict__ adj,
                                                   const float* __restrict__ wt,
                                                   const float* __restrict__ dinv,
                                                   int* __restrict__ cursor,
                                                   int2* __restrict__ col)
{
    int e = blockIdx.x * 256 + threadIdx.x;
    if (e >= N_EDGES) return;
    int s = adj[e];
    int d = adj[N_EDGES + e];
    int pos = atomicAdd(&cursor[d], 1);
    int2 c;
    c.x = s;
    c.y = __float_as_int(dinv[s] * wt[e] * dinv[d]);
    col[pos] = c;
}

// ---------------------------------------------------------------- GEMM
// C[M,NC] = A[M,K] @ W[K,NC]  (+bias+relu if BIASRELU) (BN on A if HASBN)
// Each thread owns cols {4g..4g+3} and {NC/2+4g..+3}, g = t % (NC/8),
// and RPT rows -> w_t row reads are contiguous 16B/lane (bank-clean).
template<int NC, bool BIASRELU, bool HASBN>
__global__ __launch_bounds__(256) void gemm_kernel(const float* __restrict__ A,
                                                   const float* __restrict__ W,
                                                   const float* __restrict__ bias,
                                                   const float* __restrict__ scsh,
                                                   float* __restrict__ C,
                                                   int M, int K)
{
    constexpr int BM = 128, BK = 64;
    constexpr int COLG = NC / 8;                 // 16 (NC=128) / 8 (NC=64)
    constexpr int RPT  = (BM * COLG) / 256;      // 8 / 4
    __shared__ float a_t[BM][BK + 2];
    __shared__ float w_t[BK][NC];

    int t    = threadIdx.x;
    int m0   = blockIdx.x * BM;
    int g    = t % COLG;
    int c_lo = g * 4;
    int c_hi = NC / 2 + c_lo;
    int r0   = (t / COLG) * RPT;

    float acc[RPT][8];
    #pragma unroll
    for (int j = 0; j < RPT; ++j)
        #pragma unroll
        for (int i = 0; i < 8; ++i) acc[j][i] = 0.f;

    for (int k0 = 0; k0 < K; k0 += BK) {
        // ---- stage W[k0:k0+BK, :]
        constexpr int WF4 = BK * NC / 4 / 256;   // 8 / 4
        #pragma unroll
        for (int i = 0; i < WF4; ++i) {
            int idx = t + i * 256;
            int kr  = idx / (NC / 4);
            int c4  = (idx % (NC / 4)) * 4;
            float4 v = make_float4(0.f, 0.f, 0.f, 0.f);
            if (k0 + kr < K) v = *(const float4*)&W[(size_t)(k0 + kr) * NC + c4];
            *(float4*)&w_t[kr][c4] = v;
        }
        // ---- stage A[m0:m0+BM, k0:k0+BK] (optionally BN-transformed)
        #pragma unroll
        for (int i = 0; i < BM * BK / 4 / 256; ++i) {
            int idx = t + i * 256;
            int ar  = idx / (BK / 4);
            int ac  = (idx % (BK / 4)) * 4;
            float4 v = make_float4(0.f, 0.f, 0.f, 0.f);
            int m = m0 + ar, k = k0 + ac;
            if (m < M && k < K) {
                v = *(const float4*)&A[(size_t)m * K + k];
                if (HASBN) {
                    float4 sc = *(const float4*)&scsh[k];
                    float4 sh = *(const float4*)&scsh[NHID + k];
                    v.x = v.x * sc.x + sh.x;
                    v.y = v.y * sc.y + sh.y;
                    v.z = v.z * sc.z + sh.z;
                    v.w = v.w * sc.w + sh.w;
                }
            }
            a_t[ar][ac]     = v.x;
            a_t[ar][ac + 1] = v.y;
            a_t[ar][ac + 2] = v.z;
            a_t[ar][ac + 3] = v.w;
        }
        __syncthreads();

        #pragma unroll 8
        for (int kk = 0; kk < BK; ++kk) {
            float4 w0 = *(float4*)&w_t[kk][c_lo];
            float4 w1 = *(float4*)&w_t[kk][c_hi];
            #pragma unroll
            for (int j = 0; j < RPT; ++j) {
                float a = a_t[r0 + j][kk];
                acc[j][0] += a * w0.x; acc[j][1] += a * w0.y;
                acc[j][2] += a * w0.z; acc[j][3] += a * w0.w;
                acc[j][4] += a * w1.x; acc[j][5] += a * w1.y;
                acc[j][6] += a * w1.z; acc[j][7] += a * w1.w;
            }
        }
        __syncthreads();
    }

    float4 b0, b1;
    if (BIASRELU) {
        b0 = *(const float4*)&bias[c_lo];
        b1 = *(const float4*)&bias[c_hi];
    }
    #pragma unroll
    for (int j = 0; j < RPT; ++j) {
        int m = m0 + r0 + j;
        if (m >= M) continue;
        float4 o0 = make_float4(acc[j][0], acc[j][1], acc[j][2], acc[j][3]);
        float4 o1 = make_float4(acc[j][4], acc[j][5], acc[j][6], acc[j][7]);
        if (BIASRELU) {
            o0.x = fmaxf(o0.x + b0.x, 0.f); o0.y = fmaxf(o0.y + b0.y, 0.f);
            o0.z = fmaxf(o0.z + b0.z, 0.f); o0.w = fmaxf(o0.w + b0.w, 0.f);
            o1.x = fmaxf(o1.x + b1.x, 0.f); o1.y = fmaxf(o1.y + b1.y, 0.f);
            o1.z = fmaxf(o1.z + b1.z, 0.f); o1.w = fmaxf(o1.w + b1.w, 0.f);
        }
        *(float4*)&C[(size_t)m * NC + c_lo] = o0;
        *(float4*)&C[(size_t)m * NC + c_hi] = o1;
    }
}

// ----------------------------------------------- fc1 fused concat GEMM
// C = relu([x | BN1(h1) | BN2(h2)] @ W + b), K = 200+128+128 = 456 (pad 512)
__global__ __launch_bounds__(256) void fc1_kernel(const float* __restrict__ x,
                                                  const float* __restrict__ h1,
                                                  const float* __restrict__ s1,
                                                  const float* __restrict__ h2,
                                                  const float* __restrict__ s2,
                                                  const float* __restrict__ W,
                                                  const float* __restrict__ bias,
                                                  float* __restrict__ C, int M)
{
    constexpr int NC = NHID, BM = 128, BK = 64, KTOT = NFEAT + 2 * NHID; // 456
    constexpr int COLG = NC / 8, RPT = (BM * COLG) / 256;                // 16, 8
    __shared__ float a_t[BM][BK + 2];
    __shared__ float w_t[BK][NC];

    int t    = threadIdx.x;
    int m0   = blockIdx.x * BM;
    int g    = t % COLG;
    int c_lo = g * 4;
    int c_hi = NC / 2 + c_lo;
    int r0   = (t / COLG) * RPT;

    float acc[RPT][8];
    #pragma unroll
    for (int j = 0; j < RPT; ++j)
        #pragma unroll
        for (int i = 0; i < 8; ++i) acc[j][i] = 0.f;

    for (int k0 = 0; k0 < 512; k0 += BK) {
        #pragma unroll
        for (int i = 0; i < 8; ++i) {
            int idx = t + i * 256;
            int kr  = idx / (NC / 4);
            int c4  = (idx % (NC / 4)) * 4;
            float4 v = make_float4(0.f, 0.f, 0.f, 0.f);
            if (k0 + kr < KTOT) v = *(const float4*)&W[(size_t)(k0 + kr) * NC + c4];
            *(float4*)&w_t[kr][c4] = v;
        }
        #pragma unroll
        for (int i = 0; i < BM * BK / 4 / 256; ++i) {
            int idx = t + i * 256;
            int ar  = idx / (BK / 4);
            int ac  = (idx % (BK / 4)) * 4;
            int m   = m0 + ar, kc = k0 + ac;
            float4 v = make_float4(0.f, 0.f, 0.f, 0.f);
            if (m < M) {
                if (kc < NFEAT) {
                    v = *(const float4*)&x[(size_t)m * NFEAT + kc];
                } else if (kc < NFEAT + NHID) {
                    int k = kc - NFEAT;
                    v = *(const float4*)&h1[(size_t)m * NHID + k];
                    float4 sc = *(const float4*)&s1[k];
                    float4 sh = *(const float4*)&s1[NHID + k];
                    v.x = v.x * sc.x + sh.x; v.y = v.y * sc.y + sh.y;
                    v.z = v.z * sc.z + sh.z; v.w = v.w * sc.w + sh.w;
                } else if (kc < KTOT) {
                    int k = kc - NFEAT - NHID;
                    v = *(const float4*)&h2[(size_t)m * NHID + k];
                    float4 sc = *(const float4*)&s2[k];
                    float4 sh = *(const float4*)&s2[NHID + k];
                    v.x = v.x * sc.x + sh.x; v.y = v.y * sc.y + sh.y;
                    v.z = v.z * sc.z + sh.z; v.w = v.w * sc.w + sh.w;
                }
            }
            a_t[ar][ac]     = v.x;
            a_t[ar][ac + 1] = v.y;
            a_t[ar][ac + 2] = v.z;
            a_t[ar][ac + 3] = v.w;
        }
        __syncthreads();

        #pragma unroll 8
        for (int kk = 0; kk < BK; ++kk) {
            float4 w0 = *(float4*)&w_t[kk][c_lo];
            float4 w1 = *(float4*)&w_t[kk][c_hi];
            #pragma unroll
            for (int j = 0; j < RPT; ++j) {
                float a = a_t[r0 + j][kk];
                acc[j][0] += a * w0.x; acc[j][1] += a * w0.y;
                acc[j][2] += a * w0.z; acc[j][3] += a * w0.w;
                acc[j][4] += a * w1.x; acc[j][5] += a * w1.y;
                acc[j][6] += a * w1.z; acc[j][7] += a * w1.w;
            }
        }
        __syncthreads();
    }

    float4 b0 = *(const float4*)&bias[c_lo];
    float4 b1 = *(const float4*)&bias[c_hi];
    #pragma unroll
    for (int j = 0; j < RPT; ++j) {
        int m = m0 + r0 + j;
        if (m >= M) continue;
        float4 o0 = make_float4(fmaxf(acc[j][0] + b0.x, 0.f), fmaxf(acc[j][1] + b0.y, 0.f),
                                fmaxf(acc[j][2] + b0.z, 0.f), fmaxf(acc[j][3] + b0.w, 0.f));
        float4 o1 = make_float4(fmaxf(acc[j][4] + b1.x, 0.f), fmaxf(acc[j][5] + b1.y, 0.f),
                                fmaxf(acc[j][6] + b1.z, 0.f), fmaxf(acc[j][7] + b1.w, 0.f));
        *(float4*)&C[(size_t)m * NC + c_lo] = o0;
        *(float4*)&C[(size_t)m * NC + c_hi] = o1;
    }
}

// --------------------------------------------------------- aggregation
// out[n,f] = relu( dinv[n]^2 * h[n,f] + sum_e norm[e]*h[src[e],f] + b[f] )
// One node per wave; edge loop unrolled x4 for memory-level parallelism.
__global__ __launch_bounds__(256) void agg_kernel(const float* __restrict__ h,
                                                  const float* __restrict__ bias,
                                                  const float* __restrict__ dinv,
                                                  const int* __restrict__ rowptr,
                                                  const int2* __restrict__ col,
                                                  float* __restrict__ out)
{
    int node = blockIdx.x * 4 + (threadIdx.x >> 6);
    if (node >= N_NODES) return;
    int lane = threadIdx.x & 63;
    int f0 = lane * 2;

    float di = dinv[node];
    float2 hv = *(const float2*)&h[(size_t)node * NHID + f0];
    float ax = di * di * hv.x;
    float ay = di * di * hv.y;

    int e = rowptr[node], end = rowptr[node + 1];
    for (; e + 4 <= end; e += 4) {
        int2 c0 = col[e],     c1 = col[e + 1];
        int2 c2 = col[e + 2], c3 = col[e + 3];
        float2 v0 = *(const float2*)&h[(size_t)c0.x * NHID + f0];
        float2 v1 = *(const float2*)&h[(size_t)c1.x * NHID + f0];
        float2 v2 = *(const float2*)&h[(size_t)c2.x * NHID + f0];
        float2 v3 = *(const float2*)&h[(size_t)c3.x * NHID + f0];
        float n0 = __int_as_float(c0.y), n1 = __int_as_float(c1.y);
        float n2 = __int_as_float(c2.y), n3 = __int_as_float(c3.y);
        ax += n0 * v0.x + n1 * v1.x + n2 * v2.x + n3 * v3.x;
        ay += n0 * v0.y + n1 * v1.y + n2 * v2.y + n3 * v3.y;
    }
    for (; e < end; ++e) {
        int2 c = col[e];
        float2 v = *(const float2*)&h[(size_t)c.x * NHID + f0];
        float n = __int_as_float(c.y);
        ax += n * v.x;
        ay += n * v.y;
    }
    float2 b = *(const float2*)&bias[f0];
    float2 o;
    o.x = fmaxf(ax + b.x, 0.f);
    o.y = fmaxf(ay + b.y, 0.f);
    *(float2*)&out[(size_t)node * NHID + f0] = o;
}

// --------------------------------------------------------------- stats
__global__ __launch_bounds__(256) void stats_kernel(const float* __restrict__ h,
                                                    float* __restrict__ st)
{
    __shared__ float ls[256], ls2[256];
    int t = threadIdx.x;
    int c = t & 127, half = t >> 7;
    float s = 0.f, s2 = 0.f;
    for (int r = blockIdx.x * 2 + half; r < N_NODES; r += gridDim.x * 2) {
        float v = h[(size_t)r * NHID + c];
        s += v; s2 += v * v;
    }
    ls[t] = s; ls2[t] = s2; __syncthreads();
    if (half == 0) {
        s  += ls[t + 128];
        s2 += ls2[t + 128];
        atomicAdd(&st[c], s);
        atomicAdd(&st[128 + c], s2);
    }
}

// --------------------------------------------------------- bn finalize
__global__ __launch_bounds__(128) void bn_finalize(const float* __restrict__ st,
                                                   const float* __restrict__ g,
                                                   const float* __restrict__ beta,
                                                   float* __restrict__ scsh)
{
    int c = threadIdx.x;
    float mean = st[c] / (float)N_NODES;
    float var  = st[128 + c] / (float)N_NODES - mean * mean;
    float inv  = rsqrtf(var + BN_EPS);
    float sc   = g[c] * inv;
    scsh[c]        = sc;
    scsh[NHID + c] = beta[c] - mean * sc;
}

// ---------------------------------------------------------------- host
extern "C" void kernel_launch(void* const* d_in, const int* in_sizes, int n_in,
                              void* d_out, int out_size, void* d_ws, size_t ws_size,
                              hipStream_t stream)
{
    const float* x     = (const float*)d_in[0];
    const int*   adj   = (const int*)d_in[1];
    const float* wt    = (const float*)d_in[2];
    const float* W1    = (const float*)d_in[3];
    const float* b1    = (const float*)d_in[4];
    const float* W2    = (const float*)d_in[5];
    const float* b2    = (const float*)d_in[6];
    const float* g1    = (const float*)d_in[7];
    const float* beta1 = (const float*)d_in[8];
    const float* g2    = (const float*)d_in[9];
    const float* beta2 = (const float*)d_in[10];
    const float* fc1W  = (const float*)d_in[11];
    const float* fc1b  = (const float*)d_in[12];
    const float* fc2W  = (const float*)d_in[13];
    const float* fc2b  = (const float*)d_in[14];
    float* out = (float*)d_out;

    // ---- workspace carve-up (256B aligned)
    char* p = (char*)d_ws;
    auto alloc = [&](size_t bytes) -> void* {
        void* r = (void*)p;
        p += (bytes + 255) & ~(size_t)255;
        return r;
    };
    float* dinv   = (float*)alloc((size_t)N_NODES * 4);        // deg -> dinv
    int*   counts = (int*)  alloc((size_t)(N_NODES + 1) * 4);
    int*   rowptr = (int*)  alloc((size_t)(N_NODES + 1) * 4);
    int*   cursor = (int*)  alloc((size_t)N_NODES * 4);
    int2*  col    = (int2*) alloc((size_t)N_EDGES * 8);        // (src, norm)
    int*   bsums  = (int*)  alloc(1024 * 4);
    float* stats  = (float*)alloc(512 * 4);                    // stats0 | stats1
    float* scsh1  = (float*)alloc(256 * 4);
    float* scsh2  = (float*)alloc(256 * 4);
    float* t_buf  = (float*)alloc((size_t)N_NODES * NHID * 4);
    float* h1     = (float*)alloc((size_t)N_NODES * NHID * 4);
    float* h2     = (float*)alloc((size_t)N_NODES * NHID * 4);

    const int gN1 = (N_NODES + 256) / 256;
    const int gE  = (N_EDGES + 255) / 256;
    const int gM  = (N_NODES + 127) / 128;

    // ---- graph preprocessing (CSR by dst, shared by both convs)
    init_kernel<<<gN1, 256, 0, stream>>>(counts, dinv, stats);
    hist_kernel<<<gE, 256, 0, stream>>>(adj, wt, counts, dinv);
    scan_block<<<SCAN_NB, 256, 0, stream>>>(counts, rowptr, bsums);
    scan_top<<<1, 512, 0, stream>>>(bsums);
    scan_add<<<SCAN_NB, 256, 0, stream>>>(rowptr, bsums, cursor, dinv);
    fill_kernel<<<gE, 256, 0, stream>>>(adj, wt, dinv, cursor, col);

    // ---- conv1: t = x@W1 ; h1 = relu(agg(t)+b1) ; BN1 -> scsh1 (applied lazily)
    gemm_kernel<NHID, false, false><<<gM, 256, 0, stream>>>(x, W1, nullptr, nullptr, t_buf, N_NODES, NFEAT);
    agg_kernel<<<(N_NODES + 3) / 4, 256, 0, stream>>>(t_buf, b1, dinv, rowptr, col, h1);
    stats_kernel<<<1024, 256, 0, stream>>>(h1, stats);
    bn_finalize<<<1, 128, 0, stream>>>(stats, g1, beta1, scsh1);

    // ---- conv2: t = BN1(h1)@W2 ; h2 = relu(agg(t)+b2) ; BN2 -> scsh2
    gemm_kernel<NHID, false, true><<<gM, 256, 0, stream>>>(h1, W2, nullptr, scsh1, t_buf, N_NODES, NHID);
    agg_kernel<<<(N_NODES + 3) / 4, 256, 0, stream>>>(t_buf, b2, dinv, rowptr, col, h2);
    stats_kernel<<<1024, 256, 0, stream>>>(h2, stats + 256);
    bn_finalize<<<1, 128, 0, stream>>>(stats + 256, g2, beta2, scsh2);

    // ---- fc1 fused over concat [x | BN1(h1) | BN2(h2)]
    fc1_kernel<<<gM, 256, 0, stream>>>(x, h1, scsh1, h2, scsh2, fc1W, fc1b, t_buf, N_NODES);

    // ---- fc2: out = relu(t @ fc2W + fc2b)
    gemm_kernel<NOUT, true, false><<<gM, 256, 0, stream>>>(t_buf, fc2W, fc2b, nullptr, out, N_NODES, NHID);
}